// Round 8
// baseline (26.698 us; speedup 1.0000x reference)
//
#include <hip/hip_runtime.h>

#define NT 256

// ============================================================================
// 4 lanes per problem with (row-parity, col-half) ownership:
//   lane q = 2*r0 + ch (r0 = q>>1, ch = q&1) owns, for every 8x8 matrix,
//   rows {r0, r0+2, r0+4, r0+6} and columns {4ch .. 4ch+3}.
// Why: each lane's float4 chunks per matrix are {q, q+4, q+8, q+12}, so one
// load instruction covers a FULL aligned 64B line per quad (16 fully-consumed
// lines per wave-instr) instead of 64 scattered lines -> kills the VMEM
// scatter tax of the old consecutive-row-pair layout.
// Storage: M[lr*2+lc] : v2f = (M[2lr+r0][4ch+2lc], M[2lr+r0][4ch+2lc+1]),
// lr=0..3, lc=0..1. Cross-lane = DPP quad_perm, all patterns compile-time.
// Runtime r0/ch only select vector COMPONENTS (cndmask), never array indices.
// ============================================================================

typedef float v2f __attribute__((ext_vector_type(2)));

template <int CTRL>
__device__ __forceinline__ float qbp(float x) {
    return __int_as_float(__builtin_amdgcn_mov_dpp(
        __float_as_int(x), CTRL, 0xF, 0xF, true));
}
__device__ __forceinline__ v2f pkfma(v2f a, v2f b, v2f c) {
    return __builtin_elementwise_fma(a, b, c);   // -> v_pk_fma_f32
}

// acc += SGN * X@Y, contribution of contraction index K (global col of X /
// global row of K). X-col owner: lane (r0, K>>2); Y-row owner: lane (K&1, ch).
template <int SGN, int K>
__device__ __forceinline__ void mmk(v2f (&acc)[8], const v2f (&X)[8],
                                    const v2f (&Y)[8]) {
    constexpr int XPAT = (K >> 2) ? 0xF5 : 0xA0;   // [1,1,3,3] : [0,0,2,2]
    constexpr int YPAT = (K & 1) ? 0xEE : 0x44;    // [2,3,2,3] : [0,1,0,1]
    constexpr int XPI  = (K & 3) >> 1;             // col-pair index at owner
    float xs[4];
#pragma unroll
    for (int lr = 0; lr < 4; ++lr) {
        const float s = (K & 1) ? X[lr * 2 + XPI].y : X[lr * 2 + XPI].x;
        xs[lr] = qbp<XPAT>(s);
    }
    v2f yv[2];
#pragma unroll
    for (int lc = 0; lc < 2; ++lc) {
        yv[lc].x = qbp<YPAT>(Y[(K >> 1) * 2 + lc].x);
        yv[lc].y = qbp<YPAT>(Y[(K >> 1) * 2 + lc].y);
    }
#pragma unroll
    for (int lr = 0; lr < 4; ++lr) {
        const float m = SGN > 0 ? xs[lr] : -xs[lr];
        const v2f xx = {m, m};
#pragma unroll
        for (int lc = 0; lc < 2; ++lc)
            acc[lr * 2 + lc] = pkfma(xx, yv[lc], acc[lr * 2 + lc]);
    }
}

template <int SGN>
__device__ __forceinline__ void mm4(v2f (&acc)[8], const v2f (&X)[8],
                                    const v2f (&Y)[8]) {
    mmk<SGN, 0>(acc, X, Y); mmk<SGN, 1>(acc, X, Y);
    mmk<SGN, 2>(acc, X, Y); mmk<SGN, 3>(acc, X, Y);
    mmk<SGN, 4>(acc, X, Y); mmk<SGN, 5>(acc, X, Y);
    mmk<SGN, 6>(acc, X, Y); mmk<SGN, 7>(acc, X, Y);
}

__global__ __launch_bounds__(NT)
void magnus6_kernel(const float* __restrict__ A,
                    const float* __restrict__ hp,
                    const float* __restrict__ y0,
                    float* __restrict__ out,
                    int B)
{
    // alpha3 spill: 4 float4 / thread = 64 B -> 16 KB/block, private column.
    __shared__ float4 lds[4][NT];

    const int tx = threadIdx.x;
    const int t  = blockIdx.x * NT + tx;
    const int p  = t >> 2;          // problem index
    const int q  = t & 3;
    if (p >= B) return;
    const int r0 = q >> 1;          // row parity owned
    const int ch = q & 1;           // col half owned
    const bool oddrow = (r0 != 0);
    const bool hihalf = (ch != 0);

    const float h    = hp[0];
    const float c_a2 = h * 1.2909944487358056f;   // h*sqrt(15)/3
    const float c_a3 = h * (10.0f / 3.0f);
    const float c_m  = 20.0f / 3.0f;

    // float4 chunk base: chunk index within problem = m*16 + q + 4i
    const float4* __restrict__ Ap =
        reinterpret_cast<const float4*>(A) + (size_t)p * 48 + q;

    v2f R1[8];   // alpha1 -> Omega0 -> Omega
    v2f R2[8];   // alpha2 -> Q
    v2f R3[8];   // C1 -> T' -> P'

    // ---- coalesced load: instr i covers one full 64B line per quad ----
#pragma unroll
    for (int i = 0; i < 4; ++i) {
        float4 f1 = Ap[4 * i];            // A1
        float4 f2 = Ap[16 + 4 * i];       // A2
        float4 f3 = Ap[32 + 4 * i];       // A3
        v2f A1lo = {f1.x, f1.y}, A1hi = {f1.z, f1.w};
        v2f A2lo = {f2.x, f2.y}, A2hi = {f2.z, f2.w};
        v2f A3lo = {f3.x, f3.y}, A3hi = {f3.z, f3.w};
        v2f al1lo = h * A2lo, al1hi = h * A2hi;            // alpha1
        R1[2 * i] = al1lo; R1[2 * i + 1] = al1hi;
        R2[2 * i]     = c_a2 * (A3lo - A1lo);              // alpha2
        R2[2 * i + 1] = c_a2 * (A3hi - A1hi);
        v2f a3lo = c_a3 * (A1lo + A3lo) - c_m * al1lo;     // alpha3
        v2f a3hi = c_a3 * (A1hi + A3hi) - c_m * al1hi;
        lds[i][tx] = make_float4(a3lo.x, a3lo.y, a3hi.x, a3hi.y);
    }

    // ---- C1 = [alpha1, alpha2] into R3 ----
#pragma unroll
    for (int i = 0; i < 8; ++i) R3[i] = (v2f){0.0f, 0.0f};
    mm4<+1>(R3, R1, R2);
    mm4<-1>(R3, R2, R1);

    // ---- T' = (C1 + 2*alpha3)/60 ----
#pragma unroll
    for (int c = 0; c < 4; ++c) {
        float4 v = lds[c][tx];
        v2f a3lo = {v.x, v.y}, a3hi = {v.z, v.w};
        const v2f k60 = {1.0f / 60.0f, 1.0f / 60.0f};
        R3[2 * c]     = pkfma(R3[2 * c],     k60, (1.0f / 30.0f) * a3lo);
        R3[2 * c + 1] = pkfma(R3[2 * c + 1], k60, (1.0f / 30.0f) * a3hi);
    }

    // ---- Q = alpha2 - alpha1@T' + T'@alpha1  (in place into R2) ----
    mm4<-1>(R2, R1, R3);
    mm4<+1>(R2, R3, R1);

    // ---- P' = T'/4 - alpha1/12 - alpha3/80 (R3); Omega0 = alpha1 + alpha3/12 (R1) ----
#pragma unroll
    for (int c = 0; c < 4; ++c) {
        float4 v = lds[c][tx];
        v2f a3lo = {v.x, v.y}, a3hi = {v.z, v.w};
        v2f t0 = R3[2 * c], t1 = R3[2 * c + 1];
        v2f a10 = R1[2 * c], a11 = R1[2 * c + 1];
        R3[2 * c]     = 0.25f * t0 - (1.0f / 12.0f) * a10 - (1.0f / 80.0f) * a3lo;
        R3[2 * c + 1] = 0.25f * t1 - (1.0f / 12.0f) * a11 - (1.0f / 80.0f) * a3hi;
        R1[2 * c]     = a10 + (1.0f / 12.0f) * a3lo;
        R1[2 * c + 1] = a11 + (1.0f / 12.0f) * a3hi;
    }

    // ---- Omega = Omega0 + P'@Q - Q@P'  (into R1) ----
    mm4<+1>(R1, R3, R2);
    mm4<-1>(R1, R2, R3);

    // ---- y = expm(Omega) @ y0, Taylor order 6 ----
    // vh[lc] = (v[4ch+2lc], v[4ch+2lc+1]); y accumulator in row layout:
    // ya[lr] for global row 2lr+r0.
    const float4 vh4 =
        reinterpret_cast<const float4*>(y0 + (size_t)p * 8)[ch];
    v2f vh[2] = {{vh4.x, vh4.y}, {vh4.z, vh4.w}};

    float isel0 = oddrow ? vh[0].y : vh[0].x;
    float isel1 = oddrow ? vh[1].y : vh[1].x;
    float ya[4];
    ya[0] = qbp<0xA0>(isel0);   // y0[2*0+r0] from half-0 owner, same parity
    ya[1] = qbp<0xA0>(isel1);
    ya[2] = qbp<0xF5>(isel0);
    ya[3] = qbp<0xF5>(isel1);

    const float inv[6] = {1.0f, 0.5f, 1.0f / 3.0f, 0.25f, 0.2f, 1.0f / 6.0f};
    float vn[4];
#pragma unroll
    for (int k = 0; k < 6; ++k) {
        float w[4];
#pragma unroll
        for (int lr = 0; lr < 4; ++lr) {
            v2f pv = pkfma(R1[lr * 2 + 1], vh[1], R1[lr * 2] * vh[0]);
            const float ph = pv.x + pv.y;            // my half partial
            w[lr] = ph + qbp<0xB1>(ph);              // + other half (q^1)
        }
#pragma unroll
        for (int lr = 0; lr < 4; ++lr) {
            vn[lr] = w[lr] * inv[k];
            ya[lr] += vn[lr];
        }
        if (k < 5) {
            // redistribute row-layout vn -> half-layout vh
            const float s0 = hihalf ? vn[2] : vn[0];   // vn[2ch]
            const float s1 = hihalf ? vn[3] : vn[1];   // vn[2ch+1]
            vh[0].x = qbp<0x44>(s0);   // even-parity source, same half
            vh[0].y = qbp<0xEE>(s0);   // odd-parity source, same half
            vh[1].x = qbp<0x44>(s1);
            vh[1].y = qbp<0xEE>(s1);
        }
    }

    // ---- store: rows 2lr+r0; only ch==0 lanes write (ch pair is identical) ----
    if (ch == 0) {
        float* ob = out + (size_t)p * 8 + r0;
        ob[0] = ya[0];
        ob[2] = ya[1];
        ob[4] = ya[2];
        ob[6] = ya[3];
    }
}

extern "C" void kernel_launch(void* const* d_in, const int* in_sizes, int n_in,
                              void* d_out, int out_size, void* d_ws, size_t ws_size,
                              hipStream_t stream)
{
    const float* A  = (const float*)d_in[0];
    const float* hp = (const float*)d_in[1];
    const float* y0 = (const float*)d_in[2];
    float* out = (float*)d_out;

    const int B = in_sizes[2] / 8;        // y0 is (B, 8)
    const int nthreads = 4 * B;           // 4 lanes per problem
    const int grid = (nthreads + NT - 1) / NT;
    magnus6_kernel<<<grid, NT, 0, stream>>>(A, hp, y0, out, B);
}

// Round 9
// 25.046 us; speedup vs baseline: 1.0659x; 1.0659x over previous
//
#include <hip/hip_runtime.h>

#define NT 256

// ============================================================================
// 4 lanes per problem (quad slot q = tid&3 owns global rows {2q, 2q+1} of all
// 8x8 matrices). Cross-lane row fetch = DPP quad_perm broadcast (VALU pipe).
// Matrices stored as column-pairs (v2f); FMAs are packed v_pk_fma_f32.
// R9 change vs R7: y0 load hoisted to the TOP of the kernel (issued with the
// A loads) and liveness-pinned, removing the ~500-700cy end-of-wave stall on
// a dependent load that sat after all compute. Everything else identical to
// the best-measured R7 structure (24.5 us).
// Live set ~60 floats: spill-proof under the allocator's 8-wave/EU budget.
// ============================================================================

typedef float v2f __attribute__((ext_vector_type(2)));

// Broadcast x from quad slot O to all 4 lanes of the quad (quad_perm[O,O,O,O]).
template <int O>
__device__ __forceinline__ float qb(float x) {
    return __int_as_float(__builtin_amdgcn_mov_dpp(
        __float_as_int(x), O * 0x55, 0xF, 0xF, true));
}
template <int O>
__device__ __forceinline__ v2f qb2(v2f y) {
    v2f r;
    r.x = qb<O>(y.x);
    r.y = qb<O>(y.y);
    return r;
}
__device__ __forceinline__ v2f pkfma(v2f a, v2f b, v2f c) {
    return __builtin_elementwise_fma(a, b, c);   // -> v_pk_fma_f32
}

// acc(2x8, col-pairs) += SGN * X(2x8) @ Y, contribution from Y's global rows
// {2O, 2O+1} (held by quad slot O as its local rows 0,1).
template <int SGN, int O>
__device__ __forceinline__ void mm4_o(v2f (&acc)[8], const v2f (&X)[8],
                                      const v2f (&Y)[8]) {
#pragma unroll
    for (int s = 0; s < 2; ++s) {            // global k = 2O + s
        v2f w2[4];
#pragma unroll
        for (int jj = 0; jj < 4; ++jj) w2[jj] = qb2<O>(Y[s * 4 + jj]);
#pragma unroll
        for (int r = 0; r < 2; ++r) {
            // X(row r, col k=2O+s) lives in pair X[r*4+O], component s.
            const float x0 = (s == 0) ? X[r * 4 + O].x : X[r * 4 + O].y;
            const float xs = (SGN > 0) ? x0 : -x0;
            const v2f xx = {xs, xs};
#pragma unroll
            for (int jj = 0; jj < 4; ++jj)
                acc[r * 4 + jj] = pkfma(xx, w2[jj], acc[r * 4 + jj]);
        }
    }
}

template <int SGN>
__device__ __forceinline__ void mm4(v2f (&acc)[8], const v2f (&X)[8],
                                    const v2f (&Y)[8]) {
    mm4_o<SGN, 0>(acc, X, Y);
    mm4_o<SGN, 1>(acc, X, Y);
    mm4_o<SGN, 2>(acc, X, Y);
    mm4_o<SGN, 3>(acc, X, Y);
}

__global__ __launch_bounds__(NT)
void magnus6_kernel(const float* __restrict__ A,
                    const float* __restrict__ hp,
                    const float* __restrict__ y0,
                    float* __restrict__ out,
                    int B)
{
    // alpha3 spill: 4 float4 / thread = 64 B -> 16 KB/block, private column,
    // no barriers; not occupancy-binding.
    __shared__ float4 lds[4][NT];

    const int tx = threadIdx.x;
    const int t  = blockIdx.x * NT + tx;
    const int p  = t >> 2;          // problem index
    const int q  = t & 3;           // quad slot: owns rows 2q, 2q+1
    if (p >= B) return;

    const float h    = hp[0];
    const float c_a2 = h * 1.2909944487358056f;   // h*sqrt(15)/3
    const float c_a3 = h * (10.0f / 3.0f);
    const float c_m  = 20.0f / 3.0f;

    // ---- EARLY y0 load: issue with the A loads, pin liveness so the
    //      compiler cannot sink it behind the whole compute chain ----
    const float2 y0v = *reinterpret_cast<const float2*>(y0 + (size_t)p * 8 + 2 * q);
    asm volatile("" :: "v"(y0v.x), "v"(y0v.y));

    // A is (B,3,8,8). My rows of A1 start at float offset p*192 + q*16.
    const float4* __restrict__ Ap =
        reinterpret_cast<const float4*>(A + (size_t)p * 192 + q * 16);

    v2f R1[8];   // alpha1 -> Omega0 -> Omega
    v2f R2[8];   // alpha2 -> Q (commutator accumulated in place)
    v2f R3[8];   // C1 -> T' -> P'

    // ---- stream-load A1,A2,A3; build alpha1(R1), alpha2(R2), alpha3(LDS) ----
    // chunk c: local row c>>1, cols (c&1)*4 .. +3  -> pairs b, b+1
#pragma unroll
    for (int c = 0; c < 4; ++c) {
        float4 v1 = Ap[c], v2 = Ap[16 + c], v3 = Ap[32 + c];
        const int b = (c >> 1) * 4 + (c & 1) * 2;
        v2f A1lo = {v1.x, v1.y}, A1hi = {v1.z, v1.w};
        v2f A2lo = {v2.x, v2.y}, A2hi = {v2.z, v2.w};
        v2f A3lo = {v3.x, v3.y}, A3hi = {v3.z, v3.w};
        v2f al1lo = h * A2lo, al1hi = h * A2hi;            // alpha1
        R1[b] = al1lo; R1[b + 1] = al1hi;
        R2[b]     = c_a2 * (A3lo - A1lo);                  // alpha2
        R2[b + 1] = c_a2 * (A3hi - A1hi);
        v2f a3lo = c_a3 * (A1lo + A3lo) - c_m * al1lo;     // alpha3
        v2f a3hi = c_a3 * (A1hi + A3hi) - c_m * al1hi;
        lds[c][tx] = make_float4(a3lo.x, a3lo.y, a3hi.x, a3hi.y);
    }

    // ---- C1 = [alpha1, alpha2] into R3 ----
#pragma unroll
    for (int i = 0; i < 8; ++i) R3[i] = (v2f){0.0f, 0.0f};
    mm4<+1>(R3, R1, R2);
    mm4<-1>(R3, R2, R1);

    // ---- T' = (C1 + 2*alpha3)/60 ----
#pragma unroll
    for (int c = 0; c < 4; ++c) {
        float4 v = lds[c][tx];
        v2f a3lo = {v.x, v.y}, a3hi = {v.z, v.w};
        const int b = (c >> 1) * 4 + (c & 1) * 2;
        const v2f k60 = {1.0f / 60.0f, 1.0f / 60.0f};
        R3[b]     = pkfma(R3[b],     k60, (1.0f / 30.0f) * a3lo);
        R3[b + 1] = pkfma(R3[b + 1], k60, (1.0f / 30.0f) * a3hi);
    }

    // ---- Q = alpha2 - alpha1@T' + T'@alpha1  (in place into R2) ----
    mm4<-1>(R2, R1, R3);
    mm4<+1>(R2, R3, R1);

    // ---- P' = T'/4 - alpha1/12 - alpha3/80 (R3); Omega0 = alpha1 + alpha3/12 (R1) ----
#pragma unroll
    for (int c = 0; c < 4; ++c) {
        float4 v = lds[c][tx];
        v2f a3lo = {v.x, v.y}, a3hi = {v.z, v.w};
        const int b = (c >> 1) * 4 + (c & 1) * 2;
        v2f t0 = R3[b], t1 = R3[b + 1];
        v2f a10 = R1[b], a11 = R1[b + 1];
        R3[b]     = 0.25f * t0 - (1.0f / 12.0f) * a10 - (1.0f / 80.0f) * a3lo;
        R3[b + 1] = 0.25f * t1 - (1.0f / 12.0f) * a11 - (1.0f / 80.0f) * a3hi;
        R1[b]     = a10 + (1.0f / 12.0f) * a3lo;
        R1[b + 1] = a11 + (1.0f / 12.0f) * a3hi;
    }

    // ---- Omega = Omega0 + P'@Q - Q@P'  (into R1) ----
    mm4<+1>(R1, R3, R2);
    mm4<-1>(R1, R2, R3);

    // ---- y = expm(Omega) @ y0, Taylor order 6; lane holds y rows 2q,2q+1 ----
    float v0 = y0v.x, v1 = y0v.y;
    float yy0 = v0, yy1 = v1;

    const float inv[6] = {1.0f, 0.5f, 1.0f / 3.0f, 0.25f, 0.2f, 1.0f / 6.0f};
#pragma unroll
    for (int k = 0; k < 6; ++k) {
        v2f acc0 = {0.0f, 0.0f}, acc1 = {0.0f, 0.0f};
        // vw[jj] = (v_global[2jj], v_global[2jj+1]) via quad broadcasts
        {
            v2f vw;
            vw.x = qb<0>(v0); vw.y = qb<0>(v1);
            acc0 = pkfma(R1[0], vw, acc0); acc1 = pkfma(R1[4], vw, acc1);
            vw.x = qb<1>(v0); vw.y = qb<1>(v1);
            acc0 = pkfma(R1[1], vw, acc0); acc1 = pkfma(R1[5], vw, acc1);
            vw.x = qb<2>(v0); vw.y = qb<2>(v1);
            acc0 = pkfma(R1[2], vw, acc0); acc1 = pkfma(R1[6], vw, acc1);
            vw.x = qb<3>(v0); vw.y = qb<3>(v1);
            acc0 = pkfma(R1[3], vw, acc0); acc1 = pkfma(R1[7], vw, acc1);
        }
        v0 = (acc0.x + acc0.y) * inv[k];
        v1 = (acc1.x + acc1.y) * inv[k];
        yy0 += v0;
        yy1 += v1;
    }

    *reinterpret_cast<float2*>(out + (size_t)p * 8 + 2 * q) = make_float2(yy0, yy1);
}

extern "C" void kernel_launch(void* const* d_in, const int* in_sizes, int n_in,
                              void* d_out, int out_size, void* d_ws, size_t ws_size,
                              hipStream_t stream)
{
    const float* A  = (const float*)d_in[0];
    const float* hp = (const float*)d_in[1];
    const float* y0 = (const float*)d_in[2];
    float* out = (float*)d_out;

    const int B = in_sizes[2] / 8;        // y0 is (B, 8)
    const int nthreads = 4 * B;           // 4 lanes per problem
    const int grid = (nthreads + NT - 1) / NT;
    magnus6_kernel<<<grid, NT, 0, stream>>>(A, hp, y0, out, B);
}